// Round 18
// baseline (199.297 us; speedup 1.0000x reference)
//
#include <hip/hip_runtime.h>
#include <math.h>

#define NTOK 8192
#define SD   4096
#define ITERS 20

typedef __attribute__((ext_vector_type(8))) short short8;
typedef __attribute__((ext_vector_type(8))) unsigned short ushort8;
typedef __attribute__((ext_vector_type(4))) unsigned short us4;
typedef __attribute__((ext_vector_type(4))) float f32x4;

__device__ inline unsigned short f2bf(float x) {
    unsigned int u = __float_as_uint(x);
    unsigned int r = (u + 0x7FFFu + ((u >> 16) & 1u)) >> 16;
    return (unsigned short)r;
}
__device__ inline float bf2f(unsigned short u) {
    return __uint_as_float((unsigned int)u << 16);
}
__device__ inline void async_cp16(const void* gsrc, void* ldst) {
    __builtin_amdgcn_global_load_lds(
        (const __attribute__((address_space(1))) unsigned int*)gsrc,
        (__attribute__((address_space(3))) unsigned int*)ldst, 16, 0, 0);
}

// ---------------- Kernel PREALL: fused WT + cgT + tlT prep ----------------
__global__ __launch_bounds__(256) void k_preall(const float* __restrict__ W, unsigned short* __restrict__ WT,
                                                const float* __restrict__ compress, const float* __restrict__ gamma,
                                                unsigned short* __restrict__ cgT,
                                                const float* __restrict__ tl_pre, const float* __restrict__ tl_al,
                                                const float* __restrict__ tl_nx,  const float* __restrict__ tl_po,
                                                unsigned short* __restrict__ tlT)
{
    const int b = blockIdx.x;
    const int tid = threadIdx.x;
    if (b < 256) {
        __shared__ float tb[64][65];
        const int k0 = (b >> 4) * 64, n0 = (b & 15) * 64;
        #pragma unroll 4
        for (int q = 0; q < 16; ++q) {
            const int idx = q * 256 + tid;
            const int r = idx >> 6, c = idx & 63;
            tb[r][c] = W[(size_t)(k0 + r) * 1024 + n0 + c];
        }
        __syncthreads();
        #pragma unroll 4
        for (int q = 0; q < 16; ++q) {
            const int idx = q * 256 + tid;
            const int n = idx >> 6, k = idx & 63;
            WT[(size_t)(n0 + n) * 1024 + k0 + k] = f2bf(tb[k][n]);
        }
    } else if (b < 320) {
        __shared__ float tb2[64][65];
        __shared__ float gsh[64];
        const int k0 = (b - 256) * 64;
        #pragma unroll 4
        for (int q = 0; q < 16; ++q) {
            const int idx = q * 256 + tid;
            const int r = idx >> 6, dd = idx & 63;
            tb2[r][dd] = compress[(size_t)(k0 + r) * 64 + dd];
        }
        if (tid < 64) gsh[tid] = gamma[k0 + tid] + 1.0f;
        __syncthreads();
        #pragma unroll 4
        for (int q = 0; q < 16; ++q) {
            const int idx = q * 256 + tid;
            const int d = idx >> 6, r = idx & 63;
            cgT[(size_t)d * SD + k0 + r] = f2bf(tb2[r][d] * gsh[r]);
        }
    } else {
        const int idx = (b - 320) * 256 + tid;
        const int k = idx / 640, n = idx - k * 640;
        float v;
        if (n < 64)       v = tl_pre[k * 64 + n];
        else if (n < 320) v = tl_al[k * 256 + (n - 64)];
        else if (n < 576) v = tl_nx[k * 256 + (n - 320)];
        else              v = tl_po[k * 64 + (n - 576)];
        tlT[(size_t)n * 64 + k] = f2bf(v);
    }
}

// ---------------- Kernel CODE5: code partials, K split 4 ways ----------------
__global__ __launch_bounds__(256) void k_code5(const float* __restrict__ s,
                                               const unsigned short* __restrict__ cgT,
                                               float* __restrict__ code_part,
                                               float* __restrict__ ssq_part)
{
    __shared__ float red[4 * 16 * 68];
    __shared__ float ssq_lds[64];
    const int tid  = threadIdx.x;
    const int lane = tid & 63;
    const int wid  = tid >> 6;
    const int q    = blockIdx.x;
    const int tok0 = blockIdx.y * 16;
    const int row  = lane & 15;
    const int kq   = lane >> 4;
    const int wk   = wid * 32;
    const int kbase = q * 1024;

    float ssq = 0.f;
    f32x4 acc[4];
    #pragma unroll
    for (int ni = 0; ni < 4; ++ni) acc[ni] = (f32x4){0.f, 0.f, 0.f, 0.f};

    const float*          srow  = s   + (size_t)(tok0 + row) * SD + kbase + wk + kq * 8;
    const unsigned short* cgrow = cgT + kbase + wk + kq * 8;

    #pragma unroll
    for (int ks = 0; ks < 8; ++ks) {
        const int kg = ks * 128;
        float4 v0 = *(const float4*)(srow + kg);
        float4 v1 = *(const float4*)(srow + kg + 4);
        ssq += v0.x*v0.x + v0.y*v0.y + v0.z*v0.z + v0.w*v0.w
             + v1.x*v1.x + v1.y*v1.y + v1.z*v1.z + v1.w*v1.w;
        short8 a;
        a[0]=(short)f2bf(v0.x); a[1]=(short)f2bf(v0.y); a[2]=(short)f2bf(v0.z); a[3]=(short)f2bf(v0.w);
        a[4]=(short)f2bf(v1.x); a[5]=(short)f2bf(v1.y); a[6]=(short)f2bf(v1.z); a[7]=(short)f2bf(v1.w);
        short8 b[4];
        #pragma unroll
        for (int ni = 0; ni < 4; ++ni)
            b[ni] = *(const short8*)(cgrow + (size_t)(ni * 16 + row) * SD + kg);
        #pragma unroll
        for (int ni = 0; ni < 4; ++ni)
            acc[ni] = __builtin_amdgcn_mfma_f32_16x16x32_bf16(a, b[ni], acc[ni], 0, 0, 0);
    }

    ssq += __shfl_xor(ssq, 16);
    ssq += __shfl_xor(ssq, 32);
    if (lane < 16) ssq_lds[wid * 16 + row] = ssq;

    #pragma unroll
    for (int ni = 0; ni < 4; ++ni)
        #pragma unroll
        for (int r = 0; r < 4; ++r)
            red[wid * 1088 + ((lane >> 4) * 4 + r) * 68 + ni * 16 + (lane & 15)] = acc[ni][r];
    __syncthreads();
    if (tid < 16)
        ssq_part[(size_t)q * NTOK + tok0 + tid] =
            ssq_lds[tid] + ssq_lds[16 + tid] + ssq_lds[32 + tid] + ssq_lds[48 + tid];
    #pragma unroll
    for (int q2 = 0; q2 < 4; ++q2) {
        const int idx = q2 * 256 + tid;
        const int tok = idx >> 6, d = idx & 63;
        float v = red[0 * 1088 + tok * 68 + d] + red[1 * 1088 + tok * 68 + d]
                + red[2 * 1088 + tok * 68 + d] + red[3 * 1088 + tok * 68 + d];
        code_part[((size_t)q * NTOK + tok0 + tok) * 64 + d] = v;
    }
}

// ---------------- Kernel SINK10: 512 threads/block; Sinkhorn on waves 0-3, phase F on all 8 ----------------
#define LGS 660
__global__ __launch_bounds__(512) void k_sink10(const float* __restrict__ s,
                                                const float* __restrict__ code_part,
                                                const float* __restrict__ ssq_part,
                                                const unsigned short* __restrict__ tlT,
                                                const float* __restrict__ a_pre_p, const float* __restrict__ H_pre,
                                                const float* __restrict__ a_al_p,  const float* __restrict__ H_al,
                                                const float* __restrict__ a_nx_p,  const float* __restrict__ H_nx,
                                                const float* __restrict__ a_po_p,  const float* __restrict__ H_po,
                                                unsigned short* __restrict__ layer_in,
                                                float* __restrict__ Pna, float* __restrict__ Pnp)
{
    __shared__ __align__(16) char smem[48576];
    unsigned short* code_sh = (unsigned short*)(smem);
    unsigned short* lg_sh   = (unsigned short*)(smem + 2304);
    float*          Pnx_sh  = (float*)(smem + 2304);
    float*          Pal_sh  = (float*)(smem + 23424);
    float*          Ppo_sh  = (float*)(smem + 40064);
    float*          ssq_sh  = (float*)(smem + 44416);
    float*          Ppre_sh = (float*)(smem + 44480);

    const int tid  = threadIdx.x;
    const int lane = tid & 63;
    const int wid  = tid >> 6;      // 0..7
    const int tok0 = blockIdx.x * 16;

    // ---- finalize code (1024 entries, 512 threads -> 2 each) ----
    float cv[2];
    #pragma unroll
    for (int q2 = 0; q2 < 2; ++q2) {
        const int idx = q2 * 512 + tid;
        const size_t off = (size_t)(tok0 + (idx >> 6)) * 64 + (idx & 63);
        cv[q2] = code_part[off] + code_part[(size_t)NTOK * 64 + off]
               + code_part[(size_t)2 * NTOK * 64 + off] + code_part[(size_t)3 * NTOK * 64 + off];
    }
    if (tid < 16) {
        float t = ssq_part[tok0 + tid] + ssq_part[NTOK + tok0 + tid]
                + ssq_part[2 * NTOK + tok0 + tid] + ssq_part[3 * NTOK + tok0 + tid];
        ssq_sh[tid] = 64.0f / fmaxf(sqrtf(t), 1e-12f);
    }
    __syncthreads();
    #pragma unroll
    for (int q2 = 0; q2 < 2; ++q2) {
        const int idx = q2 * 512 + tid;
        code_sh[(idx >> 6) * 72 + (idx & 63)] = f2bf(cv[q2] * ssq_sh[idx >> 6]);
    }
    __syncthreads();

    // ---- logits[16][640] = code @ tlcat^T (waves 0-3) ----
    if (wid < 4) {
        f32x4 acc2[10];
        #pragma unroll
        for (int ni = 0; ni < 10; ++ni) acc2[ni] = (f32x4){0.f, 0.f, 0.f, 0.f};
        const int nbase = wid * 160;
        #pragma unroll
        for (int ks = 0; ks < 2; ++ks) {
            const int ko = ks * 32 + (lane >> 4) * 8;
            short8 a = *(const short8*)(code_sh + (lane & 15) * 72 + ko);
            #pragma unroll
            for (int ni = 0; ni < 10; ++ni) {
                short8 b = *(const short8*)(tlT + (size_t)(nbase + ni * 16 + (lane & 15)) * 64 + ko);
                acc2[ni] = __builtin_amdgcn_mfma_f32_16x16x32_bf16(a, b, acc2[ni], 0, 0, 0);
            }
        }
        #pragma unroll
        for (int ni = 0; ni < 10; ++ni)
            #pragma unroll
            for (int r = 0; r < 4; ++r)
                lg_sh[((lane >> 4) * 4 + r) * LGS + nbase + ni * 16 + (lane & 15)] = f2bf(acc2[ni][r]);
    }
    __syncthreads();

    // ---- raw logits -> registers (waves 0-3), uniform barrier ----
    const int t_in = lane >> 2;
    const int sub  = lane & 3;
    float Km[4][16];

    if (wid < 2) {
        const unsigned short* lgp = lg_sh + t_in * LGS + (wid == 0 ? 64 : 320) + sub * 64;
        #pragma unroll
        for (int rr = 0; rr < 4; ++rr)
            #pragma unroll
            for (int h = 0; h < 2; ++h) {
                ushort8 rv = *(const ushort8*)(lgp + rr * 16 + h * 8);
                #pragma unroll
                for (int e = 0; e < 8; ++e) Km[rr][h * 8 + e] = bf2f(rv[e]);
            }
    } else if (wid == 2) {
        const unsigned short* lgp = lg_sh + t_in * LGS + sub * 16;
        #pragma unroll
        for (int h = 0; h < 2; ++h) {
            ushort8 rv = *(const ushort8*)(lgp + h * 8);
            #pragma unroll
            for (int e = 0; e < 8; ++e) Km[0][h * 8 + e] = bf2f(rv[e]);
        }
    } else if (wid == 3) {
        const unsigned short* lgp = lg_sh + t_in * LGS + 576 + sub * 16;
        #pragma unroll
        for (int rr = 0; rr < 4; ++rr) {
            us4 rv = *(const us4*)(lgp + rr * 4);
            #pragma unroll
            for (int e = 0; e < 4; ++e) Km[rr][e] = bf2f(rv[e]);
        }
    }
    __syncthreads();   // lg_sh dead; Pnx_sh alias safe

    // ---- linear Sinkhorns (waves 0-3) ----
    if (wid < 2) {
        const float alpha = (wid == 0) ? (*a_al_p) : (*a_nx_p);
        const float* Hp   = ((wid == 0) ? H_al : H_nx) + sub * 64;
        #pragma unroll
        for (int rr = 0; rr < 4; ++rr)
            #pragma unroll
            for (int c = 0; c < 16; ++c)
                Km[rr][c] = __expf(alpha * Km[rr][c] + Hp[rr * 16 + c]);
        float v[16], u[4];
        #pragma unroll
        for (int c = 0; c < 16; ++c) v[c] = 1.0f;
        for (int it = 0; it < ITERS; ++it) {
            #pragma unroll
            for (int rr = 0; rr < 4; ++rr) {
                float su = 0.f;
                #pragma unroll
                for (int c = 0; c < 16; ++c) su += Km[rr][c] * v[c];
                u[rr] = 0.0625f * __builtin_amdgcn_rcpf(su);
            }
            float pv[16];
            #pragma unroll
            for (int c = 0; c < 16; ++c)
                pv[c] = Km[0][c]*u[0] + Km[1][c]*u[1] + Km[2][c]*u[2] + Km[3][c]*u[3];
            #pragma unroll
            for (int c = 0; c < 16; ++c) pv[c] += __shfl_xor(pv[c], 1);
            #pragma unroll
            for (int c = 0; c < 16; ++c) pv[c] += __shfl_xor(pv[c], 2);
            #pragma unroll
            for (int c = 0; c < 16; ++c) v[c] = 0.0625f * __builtin_amdgcn_rcpf(pv[c]);
        }
        float* dst = ((wid == 0) ? Pal_sh : Pnx_sh) + t_in * 260;
        #pragma unroll
        for (int rr = 0; rr < 4; ++rr) {
            const float su16 = 16.0f * u[rr];
            #pragma unroll
            for (int c = 0; c < 16; ++c)
                dst[(sub * 4 + rr) * 16 + c] = Km[rr][c] * su16 * v[c];
        }
    } else if (wid == 2) {
        const float alpha = *a_pre_p;
        const float* Hp  = H_pre + sub * 16;
        #pragma unroll
        for (int c = 0; c < 16; ++c) Km[0][c] = __expf(alpha * Km[0][c] + Hp[c]);
        float v[16], u;
        #pragma unroll
        for (int c = 0; c < 16; ++c) v[c] = 1.0f;
        for (int it = 0; it < ITERS; ++it) {
            float su = 0.f;
            #pragma unroll
            for (int c = 0; c < 16; ++c) su += Km[0][c] * v[c];
            u = 0.25f * __builtin_amdgcn_rcpf(su);
            float pv[16];
            #pragma unroll
            for (int c = 0; c < 16; ++c) pv[c] = Km[0][c] * u;
            #pragma unroll
            for (int c = 0; c < 16; ++c) pv[c] += __shfl_xor(pv[c], 1);
            #pragma unroll
            for (int c = 0; c < 16; ++c) pv[c] += __shfl_xor(pv[c], 2);
            #pragma unroll
            for (int c = 0; c < 16; ++c) v[c] = 0.0625f * __builtin_amdgcn_rcpf(pv[c]);
        }
        const float su4 = 4.0f * u;
        #pragma unroll
        for (int c = 0; c < 16; ++c)
            Ppre_sh[t_in * 64 + sub * 16 + c] = Km[0][c] * su4 * v[c];
    } else if (wid == 3) {
        const float alpha = *a_po_p;
        const float* Hp  = H_po + sub * 16;
        #pragma unroll
        for (int rr = 0; rr < 4; ++rr)
            #pragma unroll
            for (int c = 0; c < 4; ++c)
                Km[rr][c] = __expf(alpha * Km[rr][c] + Hp[rr * 4 + c]);
        float v[4], u[4];
        #pragma unroll
        for (int c = 0; c < 4; ++c) v[c] = 1.0f;
        for (int it = 0; it < ITERS; ++it) {
            #pragma unroll
            for (int rr = 0; rr < 4; ++rr) {
                float su = 0.f;
                #pragma unroll
                for (int c = 0; c < 4; ++c) su += Km[rr][c] * v[c];
                u[rr] = 0.0625f * __builtin_amdgcn_rcpf(su);
            }
            float pv[4];
            #pragma unroll
            for (int c = 0; c < 4; ++c)
                pv[c] = Km[0][c]*u[0] + Km[1][c]*u[1] + Km[2][c]*u[2] + Km[3][c]*u[3];
            #pragma unroll
            for (int c = 0; c < 4; ++c) pv[c] += __shfl_xor(pv[c], 1);
            #pragma unroll
            for (int c = 0; c < 4; ++c) pv[c] += __shfl_xor(pv[c], 2);
            #pragma unroll
            for (int c = 0; c < 4; ++c) v[c] = 0.25f * __builtin_amdgcn_rcpf(pv[c]);
        }
        #pragma unroll
        for (int rr = 0; rr < 4; ++rr) {
            const float su16 = 16.0f * u[rr];
            #pragma unroll
            for (int c = 0; c < 4; ++c)
                Ppo_sh[t_in * 68 + (sub * 4 + rr) * 4 + c] = Km[rr][c] * su16 * v[c];
        }
    }
    __syncthreads();

    // ---- compose Pna = Pnx@Pal, Pnp = Pnx@Ppo (threads 0-255) ----
    if (tid < 256) {
        const int ct = tid >> 4;
        const int cj = tid & 15;
        const float* pnx = Pnx_sh + ct * 260;
        const float* pal = Pal_sh + ct * 260;
        const float* ppo = Ppo_sh + ct * 68;
        #pragma unroll
        for (int m = 0; m < 16; ++m) {
            float a2 = 0.f;
            #pragma unroll
            for (int t2 = 0; t2 < 16; ++t2) a2 += pnx[m * 16 + t2] * pal[t2 * 16 + cj];
            Pna[(size_t)(tok0 + ct) * 256 + m * 16 + cj] = a2;
        }
        #pragma unroll
        for (int e = 0; e < 4; ++e) {
            const int idx = cj * 4 + e;
            const int m = idx >> 2, q = idx & 3;
            float a2 = 0.f;
            #pragma unroll
            for (int t2 = 0; t2 < 16; ++t2) a2 += pnx[m * 16 + t2] * ppo[t2 * 4 + q];
            Pnp[(size_t)(tok0 + ct) * 64 + idx] = a2;
        }
    }

    // ---- phase F (all 8 waves, 2 rounds x 8 tokens): layer_in = Ppre @ s ----
    #pragma unroll
    for (int g = 0; g < 2; ++g) {
        const int t = g * 8 + wid;
        const float4* sp = (const float4*)(s + (size_t)(tok0 + t) * SD) + lane;
        const float* pp = Ppre_sh + t * 64;
        float4 sv[16];
        #pragma unroll
        for (int j = 0; j < 16; ++j) sv[j] = sp[j * 64];
        f32x4 acc4[4];
        #pragma unroll
        for (int i = 0; i < 4; ++i) acc4[i] = (f32x4){0.f, 0.f, 0.f, 0.f};
        #pragma unroll
        for (int i = 0; i < 4; ++i)
            #pragma unroll
            for (int j = 0; j < 16; ++j) {
                const float pij = pp[i * 16 + j];
                acc4[i][0] += pij * sv[j].x;
                acc4[i][1] += pij * sv[j].y;
                acc4[i][2] += pij * sv[j].z;
                acc4[i][3] += pij * sv[j].w;
            }
        unsigned short* lo = layer_in + (size_t)(tok0 + t) * 1024 + lane * 4;
        #pragma unroll
        for (int i = 0; i < 4; ++i) {
            us4 o;
            o[0] = f2bf(acc4[i][0]); o[1] = f2bf(acc4[i][1]);
            o[2] = f2bf(acc4[i][2]); o[3] = f2bf(acc4[i][3]);
            *(us4*)(lo + i * 256) = o;
        }
    }
}

// ---------------- Kernel C: layer_out(bf16) = layer_in @ WT^T via MFMA ----------------
__global__ __launch_bounds__(256) void k_gemm_bf16(const unsigned short* __restrict__ A,
                                                   const unsigned short* __restrict__ BT,
                                                   unsigned short* __restrict__ Cb)
{
    __shared__ unsigned short Abuf[128 * 48];
    __shared__ unsigned short Bbuf[128 * 48];
    const int tid  = threadIdx.x;
    const int lane = tid & 63;
    const int wid  = tid >> 6;
    const int wr   = wid >> 1, wc = wid & 1;
    const int m0 = blockIdx.y * 128, n0 = blockIdx.x * 128;

    f32x4 acc[4][4];
    #pragma unroll
    for (int mi = 0; mi < 4; ++mi)
        #pragma unroll
        for (int ni = 0; ni < 4; ++ni) acc[mi][ni] = (f32x4){0.f, 0.f, 0.f, 0.f};

    for (int k0 = 0; k0 < 1024; k0 += 32) {
        __syncthreads();
        #pragma unroll
        for (int h = 0; h < 2; ++h) {
            const int idx = h * 256 + tid;
            const int row = idx >> 2, kq = idx & 3;
            float4 av = *(const float4*)(A + (size_t)(m0 + row) * 1024 + k0 + kq * 8);
            *(float4*)(Abuf + row * 48 + kq * 8) = av;
            float4 bv = *(const float4*)(BT + (size_t)(n0 + row) * 1024 + k0 + kq * 8);
            *(float4*)(Bbuf + row * 48 + kq * 8) = bv;
        }
        __syncthreads();

        short8 a[4], b[4];
        #pragma unroll
        for (int mi = 0; mi < 4; ++mi)
            a[mi] = *(const short8*)(Abuf + (wr * 64 + mi * 16 + (lane & 15)) * 48 + (lane >> 4) * 8);
        #pragma unroll
        for (int ni = 0; ni < 4; ++ni)
            b[ni] = *(const short8*)(Bbuf + (wc * 64 + ni * 16 + (lane & 15)) * 48 + (lane >> 4) * 8);
        #pragma unroll
        for (int mi = 0; mi < 4; ++mi)
            #pragma unroll
            for (int ni = 0; ni < 4; ++ni)
                acc[mi][ni] = __builtin_amdgcn_mfma_f32_16x16x32_bf16(a[mi], b[ni], acc[mi][ni], 0, 0, 0);
    }

    #pragma unroll
    for (int mi = 0; mi < 4; ++mi)
        #pragma unroll
        for (int ni = 0; ni < 4; ++ni)
            #pragma unroll
            for (int r = 0; r < 4; ++r)
                Cb[(size_t)(m0 + wr * 64 + mi * 16 + (lane >> 4) * 4 + r) * 1024 +
                   n0 + wc * 64 + ni * 16 + (lane & 15)] = f2bf(acc[mi][ni][r]);
}

// ---------------- Kernel D3: s_next = P_na @ s + P_np @ lo, async staging ----------------
__global__ __launch_bounds__(256) void k_final3(const float* __restrict__ s,
                                                const unsigned short* __restrict__ lo_bf,
                                                const float* __restrict__ Pna,
                                                const float* __restrict__ Pnp,
                                                float* __restrict__ out)
{
    __shared__ __align__(16) float s_sh[SD];
    __shared__ __align__(16) unsigned short lo_sh[1024];
    __shared__ float Pna_sh[256];
    __shared__ float Pnp_sh[64];
    const int tid  = threadIdx.x;
    const int lane = tid & 63;
    const int wid  = tid >> 6;
    const int tok  = blockIdx.x;

    const float* gbase = s + (size_t)tok * SD + wid * 1024 + lane * 4;
    #pragma unroll
    for (int c = 0; c < 4; ++c)
        async_cp16(gbase + c * 256, s_sh + wid * 1024 + c * 256);
    if (wid < 2)
        async_cp16(lo_bf + (size_t)tok * 1024 + wid * 512 + lane * 8, lo_sh + wid * 512);
    Pna_sh[tid] = Pna[(size_t)tok * 256 + tid];
    if (tid < 64) Pnp_sh[tid] = Pnp[(size_t)tok * 64 + tid];
    __syncthreads();

    const int c = tid;
    float lov[4];
    #pragma unroll
    for (int q = 0; q < 4; ++q) lov[q] = bf2f(lo_sh[q * 256 + c]);
    #pragma unroll
    for (int m = 0; m < 16; ++m) {
        float acc = 0.f;
        #pragma unroll
        for (int j = 0; j < 16; ++j) acc += Pna_sh[m * 16 + j] * s_sh[j * 256 + c];
        #pragma unroll
        for (int q = 0; q < 4; ++q) acc += Pnp_sh[m * 4 + q] * lov[q];
        out[(size_t)tok * SD + m * 256 + c] = acc;
    }
}

extern "C" void kernel_launch(void* const* d_in, const int* in_sizes, int n_in,
                              void* d_out, int out_size, void* d_ws, size_t ws_size,
                              hipStream_t stream)
{
    const float* s        = (const float*)d_in[0];
    const float* gamma    = (const float*)d_in[1];
    const float* compress = (const float*)d_in[2];
    const float* a_pre    = (const float*)d_in[3];
    const float* tl_pre   = (const float*)d_in[4];
    const float* H_pre    = (const float*)d_in[5];
    const float* a_al     = (const float*)d_in[6];
    const float* tl_al    = (const float*)d_in[7];
    const float* H_al     = (const float*)d_in[8];
    const float* a_nx     = (const float*)d_in[9];
    const float* tl_nx    = (const float*)d_in[10];
    const float* H_nx     = (const float*)d_in[11];
    const float* a_po     = (const float*)d_in[12];
    const float* tl_po    = (const float*)d_in[13];
    const float* H_po     = (const float*)d_in[14];
    const float* W        = (const float*)d_in[15];
    float* out = (float*)d_out;

    char* p = (char*)d_ws;
    unsigned short* lo_bf    = (unsigned short*)p; p += (size_t)8192 * 1024 * 2;
    float* Pna               = (float*)p;          p += (size_t)8192 * 256 * 4;
    float* Pnp               = (float*)p;          p += (size_t)8192 * 64 * 4;
    unsigned short* layer_in = (unsigned short*)p; p += (size_t)8192 * 1024 * 2;
    unsigned short* WT       = (unsigned short*)p; p += (size_t)1024 * 1024 * 2;
    unsigned short* cgT      = (unsigned short*)p; p += (size_t)64 * SD * 2;
    unsigned short* tlT      = (unsigned short*)p; p += (size_t)640 * 64 * 2 + 128;
    float* code_part         = (float*)p;          p += (size_t)4 * NTOK * 64 * 4;
    float* ssq_part          = (float*)p;          p += (size_t)4 * NTOK * 4;

    k_preall<<<480, 256, 0, stream>>>(W, WT, compress, gamma, cgT,
                                      tl_pre, tl_al, tl_nx, tl_po, tlT);
    k_code5<<<dim3(4, 512), 256, 0, stream>>>(s, cgT, code_part, ssq_part);
    k_sink10<<<512, 512, 0, stream>>>(s, code_part, ssq_part, tlT,
                                      a_pre, H_pre, a_al, H_al,
                                      a_nx, H_nx, a_po, H_po,
                                      layer_in, Pna, Pnp);
    k_gemm_bf16<<<dim3(8, 64), 256, 0, stream>>>(layer_in, WT, lo_bf);
    k_final3<<<NTOK, 256, 0, stream>>>(s, lo_bf, Pna, Pnp, out);
}

// Round 19
// 185.247 us; speedup vs baseline: 1.0758x; 1.0758x over previous
//
#include <hip/hip_runtime.h>
#include <math.h>

#define NTOK 8192
#define SD   4096
#define ITERS 20

typedef __attribute__((ext_vector_type(8))) short short8;
typedef __attribute__((ext_vector_type(8))) unsigned short ushort8;
typedef __attribute__((ext_vector_type(4))) unsigned short us4;
typedef __attribute__((ext_vector_type(4))) float f32x4;

__device__ inline unsigned short f2bf(float x) {
    unsigned int u = __float_as_uint(x);
    unsigned int r = (u + 0x7FFFu + ((u >> 16) & 1u)) >> 16;
    return (unsigned short)r;
}
__device__ inline float bf2f(unsigned short u) {
    return __uint_as_float((unsigned int)u << 16);
}
__device__ inline void async_cp16(const void* gsrc, void* ldst) {
    __builtin_amdgcn_global_load_lds(
        (const __attribute__((address_space(1))) unsigned int*)gsrc,
        (__attribute__((address_space(3))) unsigned int*)ldst, 16, 0, 0);
}

// ---------------- Kernel PREALL: fused WT + cgT + tlT prep ----------------
__global__ __launch_bounds__(256) void k_preall(const float* __restrict__ W, unsigned short* __restrict__ WT,
                                                const float* __restrict__ compress, const float* __restrict__ gamma,
                                                unsigned short* __restrict__ cgT,
                                                const float* __restrict__ tl_pre, const float* __restrict__ tl_al,
                                                const float* __restrict__ tl_nx,  const float* __restrict__ tl_po,
                                                unsigned short* __restrict__ tlT)
{
    const int b = blockIdx.x;
    const int tid = threadIdx.x;
    if (b < 256) {
        __shared__ float tb[64][65];
        const int k0 = (b >> 4) * 64, n0 = (b & 15) * 64;
        #pragma unroll 4
        for (int q = 0; q < 16; ++q) {
            const int idx = q * 256 + tid;
            const int r = idx >> 6, c = idx & 63;
            tb[r][c] = W[(size_t)(k0 + r) * 1024 + n0 + c];
        }
        __syncthreads();
        #pragma unroll 4
        for (int q = 0; q < 16; ++q) {
            const int idx = q * 256 + tid;
            const int n = idx >> 6, k = idx & 63;
            WT[(size_t)(n0 + n) * 1024 + k0 + k] = f2bf(tb[k][n]);
        }
    } else if (b < 320) {
        __shared__ float tb2[64][65];
        __shared__ float gsh[64];
        const int k0 = (b - 256) * 64;
        #pragma unroll 4
        for (int q = 0; q < 16; ++q) {
            const int idx = q * 256 + tid;
            const int r = idx >> 6, dd = idx & 63;
            tb2[r][dd] = compress[(size_t)(k0 + r) * 64 + dd];
        }
        if (tid < 64) gsh[tid] = gamma[k0 + tid] + 1.0f;
        __syncthreads();
        #pragma unroll 4
        for (int q = 0; q < 16; ++q) {
            const int idx = q * 256 + tid;
            const int d = idx >> 6, r = idx & 63;
            cgT[(size_t)d * SD + k0 + r] = f2bf(tb2[r][d] * gsh[r]);
        }
    } else {
        const int idx = (b - 320) * 256 + tid;
        const int k = idx / 640, n = idx - k * 640;
        float v;
        if (n < 64)       v = tl_pre[k * 64 + n];
        else if (n < 320) v = tl_al[k * 256 + (n - 64)];
        else if (n < 576) v = tl_nx[k * 256 + (n - 320)];
        else              v = tl_po[k * 64 + (n - 576)];
        tlT[(size_t)n * 64 + k] = f2bf(v);
    }
}

// ---------------- Kernel CODE5: code partials, K split 4 ways ----------------
__global__ __launch_bounds__(256) void k_code5(const float* __restrict__ s,
                                               const unsigned short* __restrict__ cgT,
                                               float* __restrict__ code_part,
                                               float* __restrict__ ssq_part)
{
    __shared__ float red[4 * 16 * 68];
    __shared__ float ssq_lds[64];
    const int tid  = threadIdx.x;
    const int lane = tid & 63;
    const int wid  = tid >> 6;
    const int q    = blockIdx.x;
    const int tok0 = blockIdx.y * 16;
    const int row  = lane & 15;
    const int kq   = lane >> 4;
    const int wk   = wid * 32;
    const int kbase = q * 1024;

    float ssq = 0.f;
    f32x4 acc[4];
    #pragma unroll
    for (int ni = 0; ni < 4; ++ni) acc[ni] = (f32x4){0.f, 0.f, 0.f, 0.f};

    const float*          srow  = s   + (size_t)(tok0 + row) * SD + kbase + wk + kq * 8;
    const unsigned short* cgrow = cgT + kbase + wk + kq * 8;

    #pragma unroll
    for (int ks = 0; ks < 8; ++ks) {
        const int kg = ks * 128;
        float4 v0 = *(const float4*)(srow + kg);
        float4 v1 = *(const float4*)(srow + kg + 4);
        ssq += v0.x*v0.x + v0.y*v0.y + v0.z*v0.z + v0.w*v0.w
             + v1.x*v1.x + v1.y*v1.y + v1.z*v1.z + v1.w*v1.w;
        short8 a;
        a[0]=(short)f2bf(v0.x); a[1]=(short)f2bf(v0.y); a[2]=(short)f2bf(v0.z); a[3]=(short)f2bf(v0.w);
        a[4]=(short)f2bf(v1.x); a[5]=(short)f2bf(v1.y); a[6]=(short)f2bf(v1.z); a[7]=(short)f2bf(v1.w);
        short8 b[4];
        #pragma unroll
        for (int ni = 0; ni < 4; ++ni)
            b[ni] = *(const short8*)(cgrow + (size_t)(ni * 16 + row) * SD + kg);
        #pragma unroll
        for (int ni = 0; ni < 4; ++ni)
            acc[ni] = __builtin_amdgcn_mfma_f32_16x16x32_bf16(a, b[ni], acc[ni], 0, 0, 0);
    }

    ssq += __shfl_xor(ssq, 16);
    ssq += __shfl_xor(ssq, 32);
    if (lane < 16) ssq_lds[wid * 16 + row] = ssq;

    #pragma unroll
    for (int ni = 0; ni < 4; ++ni)
        #pragma unroll
        for (int r = 0; r < 4; ++r)
            red[wid * 1088 + ((lane >> 4) * 4 + r) * 68 + ni * 16 + (lane & 15)] = acc[ni][r];
    __syncthreads();
    if (tid < 16)
        ssq_part[(size_t)q * NTOK + tok0 + tid] =
            ssq_lds[tid] + ssq_lds[16 + tid] + ssq_lds[32 + tid] + ssq_lds[48 + tid];
    #pragma unroll
    for (int q2 = 0; q2 < 4; ++q2) {
        const int idx = q2 * 256 + tid;
        const int tok = idx >> 6, d = idx & 63;
        float v = red[0 * 1088 + tok * 68 + d] + red[1 * 1088 + tok * 68 + d]
                + red[2 * 1088 + tok * 68 + d] + red[3 * 1088 + tok * 68 + d];
        code_part[((size_t)q * NTOK + tok0 + tok) * 64 + d] = v;
    }
}

// ---------------- Kernel SINK9: fused sink (16 tok/block) + 16-deep phase F ----------------
#define LGS 660
__global__ __launch_bounds__(256) void k_sink9(const float* __restrict__ s,
                                               const float* __restrict__ code_part,
                                               const float* __restrict__ ssq_part,
                                               const unsigned short* __restrict__ tlT,
                                               const float* __restrict__ a_pre_p, const float* __restrict__ H_pre,
                                               const float* __restrict__ a_al_p,  const float* __restrict__ H_al,
                                               const float* __restrict__ a_nx_p,  const float* __restrict__ H_nx,
                                               const float* __restrict__ a_po_p,  const float* __restrict__ H_po,
                                               unsigned short* __restrict__ layer_in,
                                               float* __restrict__ Pna, float* __restrict__ Pnp)
{
    __shared__ __align__(16) char smem[48576];
    unsigned short* code_sh = (unsigned short*)(smem);
    unsigned short* lg_sh   = (unsigned short*)(smem + 2304);
    float*          Pnx_sh  = (float*)(smem + 2304);
    float*          Pal_sh  = (float*)(smem + 23424);
    float*          Ppo_sh  = (float*)(smem + 40064);
    float*          ssq_sh  = (float*)(smem + 44416);
    float*          Ppre_sh = (float*)(smem + 44480);

    const int tid  = threadIdx.x;
    const int lane = tid & 63;
    const int wid  = tid >> 6;
    const int tok0 = blockIdx.x * 16;

    // ---- finalize code ----
    float cv[4];
    #pragma unroll
    for (int q2 = 0; q2 < 4; ++q2) {
        const int idx = q2 * 256 + tid;
        const size_t off = (size_t)(tok0 + (idx >> 6)) * 64 + (idx & 63);
        cv[q2] = code_part[off] + code_part[(size_t)NTOK * 64 + off]
               + code_part[(size_t)2 * NTOK * 64 + off] + code_part[(size_t)3 * NTOK * 64 + off];
    }
    if (tid < 16) {
        float t = ssq_part[tok0 + tid] + ssq_part[NTOK + tok0 + tid]
                + ssq_part[2 * NTOK + tok0 + tid] + ssq_part[3 * NTOK + tok0 + tid];
        ssq_sh[tid] = 64.0f / fmaxf(sqrtf(t), 1e-12f);
    }
    __syncthreads();
    #pragma unroll
    for (int q2 = 0; q2 < 4; ++q2) {
        const int idx = q2 * 256 + tid;
        code_sh[(idx >> 6) * 72 + (idx & 63)] = f2bf(cv[q2] * ssq_sh[idx >> 6]);
    }
    __syncthreads();

    // ---- logits[16][640] = code @ tlcat^T ----
    {
        f32x4 acc2[10];
        #pragma unroll
        for (int ni = 0; ni < 10; ++ni) acc2[ni] = (f32x4){0.f, 0.f, 0.f, 0.f};
        const int nbase = wid * 160;
        #pragma unroll
        for (int ks = 0; ks < 2; ++ks) {
            const int ko = ks * 32 + (lane >> 4) * 8;
            short8 a = *(const short8*)(code_sh + (lane & 15) * 72 + ko);
            #pragma unroll
            for (int ni = 0; ni < 10; ++ni) {
                short8 b = *(const short8*)(tlT + (size_t)(nbase + ni * 16 + (lane & 15)) * 64 + ko);
                acc2[ni] = __builtin_amdgcn_mfma_f32_16x16x32_bf16(a, b, acc2[ni], 0, 0, 0);
            }
        }
        #pragma unroll
        for (int ni = 0; ni < 10; ++ni)
            #pragma unroll
            for (int r = 0; r < 4; ++r)
                lg_sh[((lane >> 4) * 4 + r) * LGS + nbase + ni * 16 + (lane & 15)] = f2bf(acc2[ni][r]);
    }
    __syncthreads();

    // ---- raw logits -> registers, uniform barrier ----
    const int t_in = lane >> 2;
    const int sub  = lane & 3;
    float Km[4][16];

    if (wid < 2) {
        const unsigned short* lgp = lg_sh + t_in * LGS + (wid == 0 ? 64 : 320) + sub * 64;
        #pragma unroll
        for (int rr = 0; rr < 4; ++rr)
            #pragma unroll
            for (int h = 0; h < 2; ++h) {
                ushort8 rv = *(const ushort8*)(lgp + rr * 16 + h * 8);
                #pragma unroll
                for (int e = 0; e < 8; ++e) Km[rr][h * 8 + e] = bf2f(rv[e]);
            }
    } else if (wid == 2) {
        const unsigned short* lgp = lg_sh + t_in * LGS + sub * 16;
        #pragma unroll
        for (int h = 0; h < 2; ++h) {
            ushort8 rv = *(const ushort8*)(lgp + h * 8);
            #pragma unroll
            for (int e = 0; e < 8; ++e) Km[0][h * 8 + e] = bf2f(rv[e]);
        }
    } else {
        const unsigned short* lgp = lg_sh + t_in * LGS + 576 + sub * 16;
        #pragma unroll
        for (int rr = 0; rr < 4; ++rr) {
            us4 rv = *(const us4*)(lgp + rr * 4);
            #pragma unroll
            for (int e = 0; e < 4; ++e) Km[rr][e] = bf2f(rv[e]);
        }
    }
    __syncthreads();   // lg_sh dead; Pnx_sh alias safe

    // ---- linear Sinkhorns ----
    if (wid < 2) {
        const float alpha = (wid == 0) ? (*a_al_p) : (*a_nx_p);
        const float* Hp   = ((wid == 0) ? H_al : H_nx) + sub * 64;
        #pragma unroll
        for (int rr = 0; rr < 4; ++rr)
            #pragma unroll
            for (int c = 0; c < 16; ++c)
                Km[rr][c] = __expf(alpha * Km[rr][c] + Hp[rr * 16 + c]);
        float v[16], u[4];
        #pragma unroll
        for (int c = 0; c < 16; ++c) v[c] = 1.0f;
        for (int it = 0; it < ITERS; ++it) {
            #pragma unroll
            for (int rr = 0; rr < 4; ++rr) {
                float su = 0.f;
                #pragma unroll
                for (int c = 0; c < 16; ++c) su += Km[rr][c] * v[c];
                u[rr] = 0.0625f * __builtin_amdgcn_rcpf(su);
            }
            float pv[16];
            #pragma unroll
            for (int c = 0; c < 16; ++c)
                pv[c] = Km[0][c]*u[0] + Km[1][c]*u[1] + Km[2][c]*u[2] + Km[3][c]*u[3];
            #pragma unroll
            for (int c = 0; c < 16; ++c) pv[c] += __shfl_xor(pv[c], 1);
            #pragma unroll
            for (int c = 0; c < 16; ++c) pv[c] += __shfl_xor(pv[c], 2);
            #pragma unroll
            for (int c = 0; c < 16; ++c) v[c] = 0.0625f * __builtin_amdgcn_rcpf(pv[c]);
        }
        float* dst = ((wid == 0) ? Pal_sh : Pnx_sh) + t_in * 260;
        #pragma unroll
        for (int rr = 0; rr < 4; ++rr) {
            const float su16 = 16.0f * u[rr];
            #pragma unroll
            for (int c = 0; c < 16; ++c)
                dst[(sub * 4 + rr) * 16 + c] = Km[rr][c] * su16 * v[c];
        }
    } else if (wid == 2) {
        const float alpha = *a_pre_p;
        const float* Hp  = H_pre + sub * 16;
        #pragma unroll
        for (int c = 0; c < 16; ++c) Km[0][c] = __expf(alpha * Km[0][c] + Hp[c]);
        float v[16], u;
        #pragma unroll
        for (int c = 0; c < 16; ++c) v[c] = 1.0f;
        for (int it = 0; it < ITERS; ++it) {
            float su = 0.f;
            #pragma unroll
            for (int c = 0; c < 16; ++c) su += Km[0][c] * v[c];
            u = 0.25f * __builtin_amdgcn_rcpf(su);
            float pv[16];
            #pragma unroll
            for (int c = 0; c < 16; ++c) pv[c] = Km[0][c] * u;
            #pragma unroll
            for (int c = 0; c < 16; ++c) pv[c] += __shfl_xor(pv[c], 1);
            #pragma unroll
            for (int c = 0; c < 16; ++c) pv[c] += __shfl_xor(pv[c], 2);
            #pragma unroll
            for (int c = 0; c < 16; ++c) v[c] = 0.0625f * __builtin_amdgcn_rcpf(pv[c]);
        }
        const float su4 = 4.0f * u;
        #pragma unroll
        for (int c = 0; c < 16; ++c)
            Ppre_sh[t_in * 64 + sub * 16 + c] = Km[0][c] * su4 * v[c];
    } else {
        const float alpha = *a_po_p;
        const float* Hp  = H_po + sub * 16;
        #pragma unroll
        for (int rr = 0; rr < 4; ++rr)
            #pragma unroll
            for (int c = 0; c < 4; ++c)
                Km[rr][c] = __expf(alpha * Km[rr][c] + Hp[rr * 4 + c]);
        float v[4], u[4];
        #pragma unroll
        for (int c = 0; c < 4; ++c) v[c] = 1.0f;
        for (int it = 0; it < ITERS; ++it) {
            #pragma unroll
            for (int rr = 0; rr < 4; ++rr) {
                float su = 0.f;
                #pragma unroll
                for (int c = 0; c < 4; ++c) su += Km[rr][c] * v[c];
                u[rr] = 0.0625f * __builtin_amdgcn_rcpf(su);
            }
            float pv[4];
            #pragma unroll
            for (int c = 0; c < 4; ++c)
                pv[c] = Km[0][c]*u[0] + Km[1][c]*u[1] + Km[2][c]*u[2] + Km[3][c]*u[3];
            #pragma unroll
            for (int c = 0; c < 4; ++c) pv[c] += __shfl_xor(pv[c], 1);
            #pragma unroll
            for (int c = 0; c < 4; ++c) pv[c] += __shfl_xor(pv[c], 2);
            #pragma unroll
            for (int c = 0; c < 4; ++c) v[c] = 0.25f * __builtin_amdgcn_rcpf(pv[c]);
        }
        #pragma unroll
        for (int rr = 0; rr < 4; ++rr) {
            const float su16 = 16.0f * u[rr];
            #pragma unroll
            for (int c = 0; c < 4; ++c)
                Ppo_sh[t_in * 68 + (sub * 4 + rr) * 4 + c] = Km[rr][c] * su16 * v[c];
        }
    }
    __syncthreads();

    // ---- compose Pna = Pnx@Pal, Pnp = Pnx@Ppo ----
    const int ct = tid >> 4;
    const int cj = tid & 15;
    {
        const float* pnx = Pnx_sh + ct * 260;
        const float* pal = Pal_sh + ct * 260;
        const float* ppo = Ppo_sh + ct * 68;
        #pragma unroll
        for (int m = 0; m < 16; ++m) {
            float a2 = 0.f;
            #pragma unroll
            for (int t2 = 0; t2 < 16; ++t2) a2 += pnx[m * 16 + t2] * pal[t2 * 16 + cj];
            Pna[(size_t)(tok0 + ct) * 256 + m * 16 + cj] = a2;
        }
        #pragma unroll
        for (int e = 0; e < 4; ++e) {
            const int idx = cj * 4 + e;
            const int m = idx >> 2, q = idx & 3;
            float a2 = 0.f;
            #pragma unroll
            for (int t2 = 0; t2 < 16; ++t2) a2 += pnx[m * 16 + t2] * ppo[t2 * 4 + q];
            Pnp[(size_t)(tok0 + ct) * 64 + idx] = a2;
        }
    }

    // ---- phase F (16-deep load burst): layer_in = Ppre @ s ----
    #pragma unroll
    for (int g = 0; g < 4; ++g) {
        const int t = g * 4 + wid;
        const float4* sp = (const float4*)(s + (size_t)(tok0 + t) * SD) + lane;
        const float* pp = Ppre_sh + t * 64;
        float4 sv[16];
        #pragma unroll
        for (int j = 0; j < 16; ++j) sv[j] = sp[j * 64];
        f32x4 acc4[4];
        #pragma unroll
        for (int i = 0; i < 4; ++i) acc4[i] = (f32x4){0.f, 0.f, 0.f, 0.f};
        #pragma unroll
        for (int i = 0; i < 4; ++i)
            #pragma unroll
            for (int j = 0; j < 16; ++j) {
                const float pij = pp[i * 16 + j];
                acc4[i][0] += pij * sv[j].x;
                acc4[i][1] += pij * sv[j].y;
                acc4[i][2] += pij * sv[j].z;
                acc4[i][3] += pij * sv[j].w;
            }
        unsigned short* lo = layer_in + (size_t)(tok0 + t) * 1024 + lane * 4;
        #pragma unroll
        for (int i = 0; i < 4; ++i) {
            us4 o;
            o[0] = f2bf(acc4[i][0]); o[1] = f2bf(acc4[i][1]);
            o[2] = f2bf(acc4[i][2]); o[3] = f2bf(acc4[i][3]);
            *(us4*)(lo + i * 256) = o;
        }
    }
}

// ---------------- Kernel C: layer_out(bf16) = layer_in @ WT^T via MFMA ----------------
__global__ __launch_bounds__(256) void k_gemm_bf16(const unsigned short* __restrict__ A,
                                                   const unsigned short* __restrict__ BT,
                                                   unsigned short* __restrict__ Cb)
{
    __shared__ unsigned short Abuf[128 * 48];
    __shared__ unsigned short Bbuf[128 * 48];
    const int tid  = threadIdx.x;
    const int lane = tid & 63;
    const int wid  = tid >> 6;
    const int wr   = wid >> 1, wc = wid & 1;
    const int m0 = blockIdx.y * 128, n0 = blockIdx.x * 128;

    f32x4 acc[4][4];
    #pragma unroll
    for (int mi = 0; mi < 4; ++mi)
        #pragma unroll
        for (int ni = 0; ni < 4; ++ni) acc[mi][ni] = (f32x4){0.f, 0.f, 0.f, 0.f};

    for (int k0 = 0; k0 < 1024; k0 += 32) {
        __syncthreads();
        #pragma unroll
        for (int h = 0; h < 2; ++h) {
            const int idx = h * 256 + tid;
            const int row = idx >> 2, kq = idx & 3;
            float4 av = *(const float4*)(A + (size_t)(m0 + row) * 1024 + k0 + kq * 8);
            *(float4*)(Abuf + row * 48 + kq * 8) = av;
            float4 bv = *(const float4*)(BT + (size_t)(n0 + row) * 1024 + k0 + kq * 8);
            *(float4*)(Bbuf + row * 48 + kq * 8) = bv;
        }
        __syncthreads();

        short8 a[4], b[4];
        #pragma unroll
        for (int mi = 0; mi < 4; ++mi)
            a[mi] = *(const short8*)(Abuf + (wr * 64 + mi * 16 + (lane & 15)) * 48 + (lane >> 4) * 8);
        #pragma unroll
        for (int ni = 0; ni < 4; ++ni)
            b[ni] = *(const short8*)(Bbuf + (wc * 64 + ni * 16 + (lane & 15)) * 48 + (lane >> 4) * 8);
        #pragma unroll
        for (int mi = 0; mi < 4; ++mi)
            #pragma unroll
            for (int ni = 0; ni < 4; ++ni)
                acc[mi][ni] = __builtin_amdgcn_mfma_f32_16x16x32_bf16(a[mi], b[ni], acc[mi][ni], 0, 0, 0);
    }

    #pragma unroll
    for (int mi = 0; mi < 4; ++mi)
        #pragma unroll
        for (int ni = 0; ni < 4; ++ni)
            #pragma unroll
            for (int r = 0; r < 4; ++r)
                Cb[(size_t)(m0 + wr * 64 + mi * 16 + (lane >> 4) * 4 + r) * 1024 +
                   n0 + wc * 64 + ni * 16 + (lane & 15)] = f2bf(acc[mi][ni][r]);
}

// ---------------- Kernel D3: s_next = P_na @ s + P_np @ lo, async staging ----------------
__global__ __launch_bounds__(256) void k_final3(const float* __restrict__ s,
                                                const unsigned short* __restrict__ lo_bf,
                                                const float* __restrict__ Pna,
                                                const float* __restrict__ Pnp,
                                                float* __restrict__ out)
{
    __shared__ __align__(16) float s_sh[SD];
    __shared__ __align__(16) unsigned short lo_sh[1024];
    __shared__ float Pna_sh[256];
    __shared__ float Pnp_sh[64];
    const int tid  = threadIdx.x;
    const int lane = tid & 63;
    const int wid  = tid >> 6;
    const int tok  = blockIdx.x;

    const float* gbase = s + (size_t)tok * SD + wid * 1024 + lane * 4;
    #pragma unroll
    for (int c = 0; c < 4; ++c)
        async_cp16(gbase + c * 256, s_sh + wid * 1024 + c * 256);
    if (wid < 2)
        async_cp16(lo_bf + (size_t)tok * 1024 + wid * 512 + lane * 8, lo_sh + wid * 512);
    Pna_sh[tid] = Pna[(size_t)tok * 256 + tid];
    if (tid < 64) Pnp_sh[tid] = Pnp[(size_t)tok * 64 + tid];
    __syncthreads();

    const int c = tid;
    float lov[4];
    #pragma unroll
    for (int q = 0; q < 4; ++q) lov[q] = bf2f(lo_sh[q * 256 + c]);
    #pragma unroll
    for (int m = 0; m < 16; ++m) {
        float acc = 0.f;
        #pragma unroll
        for (int j = 0; j < 16; ++j) acc += Pna_sh[m * 16 + j] * s_sh[j * 256 + c];
        #pragma unroll
        for (int q = 0; q < 4; ++q) acc += Pnp_sh[m * 4 + q] * lov[q];
        out[(size_t)tok * SD + m * 256 + c] = acc;
    }
}

extern "C" void kernel_launch(void* const* d_in, const int* in_sizes, int n_in,
                              void* d_out, int out_size, void* d_ws, size_t ws_size,
                              hipStream_t stream)
{
    const float* s        = (const float*)d_in[0];
    const float* gamma    = (const float*)d_in[1];
    const float* compress = (const float*)d_in[2];
    const float* a_pre    = (const float*)d_in[3];
    const float* tl_pre   = (const float*)d_in[4];
    const float* H_pre    = (const float*)d_in[5];
    const float* a_al     = (const float*)d_in[6];
    const float* tl_al    = (const float*)d_in[7];
    const float* H_al     = (const float*)d_in[8];
    const float* a_nx     = (const float*)d_in[9];
    const float* tl_nx    = (const float*)d_in[10];
    const float* H_nx     = (const float*)d_in[11];
    const float* a_po     = (const float*)d_in[12];
    const float* tl_po    = (const float*)d_in[13];
    const float* H_po     = (const float*)d_in[14];
    const float* W        = (const float*)d_in[15];
    float* out = (float*)d_out;

    char* p = (char*)d_ws;
    unsigned short* lo_bf    = (unsigned short*)p; p += (size_t)8192 * 1024 * 2;
    float* Pna               = (float*)p;          p += (size_t)8192 * 256 * 4;
    float* Pnp               = (float*)p;          p += (size_t)8192 * 64 * 4;
    unsigned short* layer_in = (unsigned short*)p; p += (size_t)8192 * 1024 * 2;
    unsigned short* WT       = (unsigned short*)p; p += (size_t)1024 * 1024 * 2;
    unsigned short* cgT      = (unsigned short*)p; p += (size_t)64 * SD * 2;
    unsigned short* tlT      = (unsigned short*)p; p += (size_t)640 * 64 * 2 + 128;
    float* code_part         = (float*)p;          p += (size_t)4 * NTOK * 64 * 4;
    float* ssq_part          = (float*)p;          p += (size_t)4 * NTOK * 4;

    k_preall<<<480, 256, 0, stream>>>(W, WT, compress, gamma, cgT,
                                      tl_pre, tl_al, tl_nx, tl_po, tlT);
    k_code5<<<dim3(4, 512), 256, 0, stream>>>(s, cgT, code_part, ssq_part);
    k_sink9<<<512, 256, 0, stream>>>(s, code_part, ssq_part, tlT,
                                     a_pre, H_pre, a_al, H_al,
                                     a_nx, H_nx, a_po, H_po,
                                     layer_in, Pna, Pnp);
    k_gemm_bf16<<<dim3(8, 64), 256, 0, stream>>>(layer_in, WT, lo_bf);
    k_final3<<<NTOK, 256, 0, stream>>>(s, lo_bf, Pna, Pnp, out);
}